// Round 11
// baseline (342.813 us; speedup 1.0000x reference)
//
#include <hip/hip_runtime.h>
#include <cstdint>
#include <cstddef>

#define IN_F 4096
#define OUT_F 4096

typedef __attribute__((ext_vector_type(8))) short bf16x8;
typedef __attribute__((ext_vector_type(4))) float f32x4;

__device__ __forceinline__ ushort f32_bf16_rne(float f) {
    uint32_t u = __builtin_bit_cast(uint32_t, f);
    uint32_t r = (u + 0x7FFFu + ((u >> 16) & 1u)) >> 16;
    return (ushort)r;
}

__device__ __forceinline__ void gload_lds16(const void* g, void* l) {
    __builtin_amdgcn_global_load_lds(
        (const __attribute__((address_space(1))) uint32_t*)g,
        (__attribute__((address_space(3))) uint32_t*)l,
        16, 0, 0);
}

__device__ __forceinline__ void bar() {
    asm volatile("s_barrier" ::: "memory");
}

// ---------- deterministic |W| reduction (fixed order, no atomics) ----------
__global__ void reduce_abs1(const float* __restrict__ W, float* __restrict__ part) {
    __shared__ float sm[256];
    const int b = blockIdx.x, t = threadIdx.x;
    const float* p = W + (size_t)b * 4096;
    float s = 0.f;
#pragma unroll
    for (int j = 0; j < 16; ++j) s += fabsf(p[t + 256 * j]);
    sm[t] = s;
    __syncthreads();
    for (int w = 128; w > 0; w >>= 1) {
        if (t < w) sm[t] += sm[t + w];
        __syncthreads();
    }
    if (t == 0) part[b] = sm[0];
}

__global__ void reduce_abs2(const float* __restrict__ part, float* __restrict__ scale) {
    __shared__ float sm[256];
    const int t = threadIdx.x;
    float s = 0.f;
#pragma unroll
    for (int j = 0; j < 16; ++j) s += part[t + 256 * j];
    sm[t] = s;
    __syncthreads();
    for (int w = 128; w > 0; w >>= 1) {
        if (t < w) sm[t] += sm[t + w];
        __syncthreads();
    }
    if (t == 0) {
        float m = sm[0] / 16777216.0f;
        *scale = fmaxf(m, 1e-8f);
    }
}

// ---------- quantize W -> bf16 {-2,-1,0,1,2} (exact in bf16) ----------
__global__ void quantize_w(const float* __restrict__ W, ushort* __restrict__ wq,
                           const float* __restrict__ scale_p) {
    const int i = blockIdx.x * 256 + threadIdx.x;
    const float s = *scale_p;
    float4 v = ((const float4*)W)[i];
    float q0 = fminf(fmaxf(rintf(v.x / s), -2.f), 2.f);
    float q1 = fminf(fmaxf(rintf(v.y / s), -2.f), 2.f);
    float q2 = fminf(fmaxf(rintf(v.z / s), -2.f), 2.f);
    float q3 = fminf(fmaxf(rintf(v.w / s), -2.f), 2.f);
    ushort4 o;
    o.x = f32_bf16_rne(q0); o.y = f32_bf16_rne(q1);
    o.z = f32_bf16_rne(q2); o.w = f32_bf16_rne(q3);
    ((ushort4*)wq)[i] = o;
}

// ---------- cast x -> bf16 (RNE) ----------
__global__ void cast_x(const float* __restrict__ X, ushort* __restrict__ xh) {
    const int i = blockIdx.x * 256 + threadIdx.x;
    float4 v = ((const float4*)X)[i];
    ushort4 o;
    o.x = f32_bf16_rne(v.x); o.y = f32_bf16_rne(v.y);
    o.z = f32_bf16_rne(v.z); o.w = f32_bf16_rne(v.w);
    ((ushort4*)xh)[i] = o;
}

// ======= 256x256 GEMM, BK=32, 64-KiB LDS -> 2 blocks/CU (R11) ==============
// C = scale * (A @ B^T).  A:[M][K] bf16, B:[N][K] bf16 (both K-contiguous).
// 512 threads = 8 waves (2M x 4N); per-wave 128x64 output (acc[8][4], AGPR).
//
// R11 diagnosis (R3-R10 all 41-47% MfmaUtil): with 128-KiB LDS the kernel is
// 1 block/CU -- 8 waves in barrier lockstep, so the MFMA pipe (~2400 cyc/
// K-tile) and the shared LDS unit (~2500 cyc) SERIALIZE (measured 4930 =
// sum); no source-level ordering fixed it.  Fix: BK=32 halves the LDS
// double-buffer to 64 KiB -> 2 INDEPENDENT blocks/CU; when one block sits at
// a barrier or read cluster, the sibling block's waves feed the MFMA pipes
// (m114 implicit wave-level overlap -- the engine behind m97's 874 TF).
//
// LDS per buffer (32 KiB): A [256 rows][32 cols] @0, B same @16 KiB.
// Swizzle for the 64-B row: 16-B chunk c of row r stored at c ^ ((r>>1)&3)
// -> a frag read's 16 lanes (16 consecutive rows) spread over all 32 banks,
// 2 lanes/bank-quad = free (m136).  Applied on BOTH sides (rule #21):
// pre-swizzled global source column + XOR'd ds_read offset; LDS dest linear.
//
// Per K-tile: { stage(kt+1 -> other buf) [4 gload_lds16/thread];
//   vmcnt(4) [stage(kt) drained]; bar [publish tile kt]; setprio1;
//   12 ds_read + 32 MFMA; setprio0; lgkmcnt(0); bar }.
// WAR: stage(kt+1) overwrites tile kt-1, lgkm-drained before kt-1's end-bar.
// Tail: kt==NT-1 stages nothing -> vmcnt(0).
#define QBUF 32768

__global__ __launch_bounds__(512, 2) void qgemm256(
        const ushort* __restrict__ Ab, const ushort* __restrict__ Bq,
        float* __restrict__ C, const float* __restrict__ scale_p,
        int M, int N, int K) {
    extern __shared__ __align__(16) char smem[];

    const int t = threadIdx.x;
    const int lane = t & 63;
    const int w = t >> 6;
    const int wr = w >> 2;   // 0..1 (M half)
    const int wc = w & 3;    // 0..3 (N quarter)

    // ---- 2D XCD-aware supertiling (validated R7: FETCH 541->197 MB) ----
    const int MT = M >> 8;
    const int NTiles = N >> 8;
    int mt, nt;
    if (MT == 32 && NTiles == 16 && gridDim.x == 512) {
        const int x = blockIdx.x & 7;
        const int j = blockIdx.x >> 3;
        const int jr = j & 31;
        const int r = j >> 5;
        mt = (x & 3) * 8 + (jr & 7);
        nt = r * 8 + (x >> 2) * 4 + (jr >> 3);
    } else {
        const int nwg = gridDim.x;
        int wg = blockIdx.x;
        if ((nwg & 7) == 0) wg = (wg & 7) * (nwg >> 3) + (wg >> 3);
        mt = wg % MT; nt = wg / MT;
    }
    const int m0 = mt << 8;
    const int n0 = nt << 8;

    const int NT = K / 32;   // 128 K-tiles

    // per-lane ds_read byte offset within a [rows][64B] region:
    // row = lane&15 (+ frag offsets in bits >=4), chunk = lane>>4 (k-group),
    // swizzled chunk = (lane>>4) ^ ((row>>1)&3) = (lane>>4) ^ ((lane>>1)&3).
    const int pre = (lane & 15) * 64 +
                    ((((lane >> 4) & 3) ^ ((lane >> 1) & 3)) << 4);

    // ---- stage pointers (pre-swizzled source, linear LDS dest) ----
    const int rowA = t >> 2;                               // 0..127
    const int swc = ((t & 3) ^ ((t >> 3) & 3)) * 8;        // swizzled col (elems)
    const ushort* gA0 = Ab + (size_t)(m0 + rowA) * K + swc;
    const ushort* gA1 = Ab + (size_t)(m0 + 128 + rowA) * K + swc;
    const ushort* gB0 = Bq + (size_t)(n0 + rowA) * K + swc;
    const ushort* gB1 = Bq + (size_t)(n0 + 128 + rowA) * K + swc;
    char* lb = smem + t * 16;

    auto st = [&](uint32_t par) {
        gload_lds16(gA0, lb + par);            // A rows 0-127
        gload_lds16(gA1, lb + par + 8192);     // A rows 128-255
        gload_lds16(gB0, lb + par + 16384);    // B rows 0-127
        gload_lds16(gB1, lb + par + 24576);    // B rows 128-255
        gA0 += 32; gA1 += 32; gB0 += 32; gB1 += 32;   // advance one K-tile
    };

    const char* aBbase = smem + wr * 8192;             // wave's A half (128 rows)
    const char* bBbase = smem + 16384 + wc * 4096;     // wave's B strip (64 rows)

    f32x4 acc[8][4];
#pragma unroll
    for (int m = 0; m < 8; ++m)
#pragma unroll
        for (int n = 0; n < 4; ++n) acc[m][n] = (f32x4){0.f, 0.f, 0.f, 0.f};

    // ---- prologue: stage tile 0 into buffer 0 ----
    st(0);

    for (int kt = 0; kt < NT; ++kt) {
        const uint32_t cur = (uint32_t)(kt & 1) * QBUF;

        if (kt + 1 < NT) {
            st(cur ^ QBUF);                                  // stage tile kt+1
            asm volatile("s_waitcnt vmcnt(4)" ::: "memory"); // stage(kt) done
        } else {
            asm volatile("s_waitcnt vmcnt(0)" ::: "memory"); // tail drain
        }
        bar();  // publish tile kt

        __builtin_amdgcn_s_setprio(1);
        bf16x8 af[8], bf[4];
#pragma unroll
        for (int n = 0; n < 4; ++n)
            bf[n] = *(const bf16x8*)(bBbase + cur + n * 1024 + pre);
#pragma unroll
        for (int m = 0; m < 8; ++m)
            af[m] = *(const bf16x8*)(aBbase + cur + m * 1024 + pre);
#pragma unroll
        for (int m = 0; m < 8; ++m)
#pragma unroll
            for (int n = 0; n < 4; ++n)
                acc[m][n] = __builtin_amdgcn_mfma_f32_16x16x32_bf16(
                    af[m], bf[n], acc[m][n], 0, 0, 0);
        __builtin_amdgcn_s_setprio(0);
        // all LDS reads complete before anyone stages over this buffer
        asm volatile("s_waitcnt lgkmcnt(0)" ::: "memory");
        bar();
    }

    const float s = *scale_p;
#pragma unroll
    for (int m = 0; m < 8; ++m)
#pragma unroll
        for (int n = 0; n < 4; ++n) {
            const int col = n0 + wc * 64 + n * 16 + (lane & 15);
            const int rbase = m0 + wr * 128 + m * 16 + ((lane >> 4) << 2);
#pragma unroll
            for (int j = 0; j < 4; ++j)
                C[(size_t)(rbase + j) * N + col] = s * acc[m][n][j];
        }
}

// ---------- 128^2 fallback (validated round 2) ----------
template <bool ABF16>
__global__ __launch_bounds__(256) void qgemm(const void* __restrict__ Aptr,
                                             const ushort* __restrict__ Bq,
                                             float* __restrict__ C,
                                             const float* __restrict__ scale_p,
                                             int M, int N, int K) {
    __shared__ __align__(16) ushort sA[128 * 64];
    __shared__ __align__(16) ushort sB[128 * 64];

    const int t = threadIdx.x;
    const int lane = t & 63;
    const int w = t >> 6;
    const int wr = w >> 1, wc = w & 1;

    const int nwg = gridDim.x;
    int wg = blockIdx.x;
    if ((nwg & 7) == 0) wg = (wg & 7) * (nwg >> 3) + (wg >> 3);
    const int MT = M >> 7;
    const int mt = wg % MT;
    const int nt = wg / MT;
    const int m0 = mt * 128, n0 = nt * 128;

    const ushort* Ab = (const ushort*)Aptr;
    const float* Af = (const float*)Aptr;

    f32x4 zero = {0.f, 0.f, 0.f, 0.f};
    f32x4 acc[4][4];
#pragma unroll
    for (int m = 0; m < 4; ++m)
#pragma unroll
        for (int n = 0; n < 4; ++n) acc[m][n] = zero;

    for (int k0 = 0; k0 < K; k0 += 64) {
#pragma unroll
        for (int i = 0; i < 4; ++i) {
            int e = i * 2048 + t * 8;
            int r = e >> 6, c8 = (e >> 3) & 7;
            int srcc = (c8 ^ (r & 7)) * 8;
            gload_lds16(Bq + (size_t)(n0 + r) * K + (k0 + srcc), &sB[e]);
        }
        if constexpr (ABF16) {
#pragma unroll
            for (int i = 0; i < 4; ++i) {
                int e = i * 2048 + t * 8;
                int r = e >> 6, c8 = (e >> 3) & 7;
                int srcc = (c8 ^ (r & 7)) * 8;
                gload_lds16(Ab + (size_t)(m0 + r) * K + (k0 + srcc), &sA[e]);
            }
        } else {
#pragma unroll
            for (int i = 0; i < 4; ++i) {
                int e = i * 2048 + t * 8;
                int r = e >> 6, c = e & 63;
                const float* src = Af + (size_t)(m0 + r) * K + (k0 + c);
                float4 v0 = *(const float4*)src;
                float4 v1 = *(const float4*)(src + 4);
                bf16x8 pk;
                pk[0] = (short)f32_bf16_rne(v0.x); pk[1] = (short)f32_bf16_rne(v0.y);
                pk[2] = (short)f32_bf16_rne(v0.z); pk[3] = (short)f32_bf16_rne(v0.w);
                pk[4] = (short)f32_bf16_rne(v1.x); pk[5] = (short)f32_bf16_rne(v1.y);
                pk[6] = (short)f32_bf16_rne(v1.z); pk[7] = (short)f32_bf16_rne(v1.w);
                int byte = (r * 128 + c * 2) ^ ((r & 7) << 4);
                *(bf16x8*)((char*)sA + byte) = pk;
            }
        }
        __syncthreads();

#pragma unroll
        for (int ks = 0; ks < 2; ++ks) {
            const int kk = ks * 32 + ((lane >> 4) << 3);
            bf16x8 afr[4], bfr[4];
#pragma unroll
            for (int m = 0; m < 4; ++m) {
                int r = wr * 64 + m * 16 + (lane & 15);
                int byte = (r * 128 + kk * 2) ^ ((r & 7) << 4);
                afr[m] = *(const bf16x8*)((const char*)sA + byte);
            }
#pragma unroll
            for (int n = 0; n < 4; ++n) {
                int r = wc * 64 + n * 16 + (lane & 15);
                int byte = (r * 128 + kk * 2) ^ ((r & 7) << 4);
                bfr[n] = *(const bf16x8*)((const char*)sB + byte);
            }
#pragma unroll
            for (int m = 0; m < 4; ++m)
#pragma unroll
                for (int n = 0; n < 4; ++n)
                    acc[m][n] = __builtin_amdgcn_mfma_f32_16x16x32_bf16(
                        afr[m], bfr[n], acc[m][n], 0, 0, 0);
        }
        __syncthreads();
    }

    const float s = *scale_p;
#pragma unroll
    for (int m = 0; m < 4; ++m)
#pragma unroll
        for (int n = 0; n < 4; ++n) {
            const int col = n0 + wc * 64 + n * 16 + (lane & 15);
            const int rbase = m0 + wr * 64 + m * 16 + ((lane >> 4) << 2);
#pragma unroll
            for (int j = 0; j < 4; ++j)
                C[(size_t)(rbase + j) * N + col] = s * acc[m][n][j];
        }
}

// ---------- last-resort naive path ----------
__global__ void naive_qgemm(const float* __restrict__ X, const float* __restrict__ W,
                            float* __restrict__ out, const float* __restrict__ scale_p,
                            int M) {
    const int col = blockIdx.x * 256 + threadIdx.x;
    const int row = blockIdx.y;
    const float s = *scale_p;
    const float inv = 1.0f / s;
    const float* xr = X + (size_t)row * IN_F;
    const float* wrow = W + (size_t)col * IN_F;
    float acc = 0.f;
    for (int k = 0; k < IN_F; ++k) {
        float q = fminf(fmaxf(rintf(wrow[k] * inv), -2.f), 2.f);
        acc += xr[k] * q;
    }
    out[(size_t)row * OUT_F + col] = acc * s;
}

extern "C" void kernel_launch(void* const* d_in, const int* in_sizes, int n_in,
                              void* d_out, int out_size, void* d_ws, size_t ws_size,
                              hipStream_t stream) {
    const float* x = (const float*)d_in[0];
    const float* W = (const float*)d_in[1];
    float* out = (float*)d_out;
    const int M = in_sizes[0] / IN_F;  // 8192
    const int K = IN_F, N = OUT_F;

    char* ws = (char*)d_ws;
    const size_t OFF_PART = 512;
    const size_t OFF_WQ = OFF_PART + 4096 * sizeof(float);
    const size_t WQ_BYTES = (size_t)N * K * sizeof(ushort);
    const size_t OFF_XH = OFF_WQ + WQ_BYTES;
    const size_t XH_BYTES = (size_t)M * K * sizeof(ushort);
    float* scale = (float*)(ws + 0);
    float* part = (float*)(ws + OFF_PART);
    ushort* wq = (ushort*)(ws + OFF_WQ);
    ushort* xh = (ushort*)(ws + OFF_XH);

    if (ws_size < OFF_WQ) return;

    reduce_abs1<<<4096, 256, 0, stream>>>(W, part);
    reduce_abs2<<<1, 256, 0, stream>>>(part, scale);

    if (ws_size >= OFF_XH + XH_BYTES && (M % 256) == 0 && (N % 256) == 0) {
        quantize_w<<<(N * K / 4) / 256, 256, 0, stream>>>(W, wq, scale);
        cast_x<<<(M * K / 4) / 256, 256, 0, stream>>>(x, xh);
        (void)hipFuncSetAttribute((const void*)qgemm256,
                                  hipFuncAttributeMaxDynamicSharedMemorySize,
                                  65536);
        qgemm256<<<(M / 256) * (N / 256), 512, 65536, stream>>>(
            xh, wq, out, scale, M, N, K);
    } else if (ws_size >= OFF_XH + XH_BYTES) {
        quantize_w<<<(N * K / 4) / 256, 256, 0, stream>>>(W, wq, scale);
        cast_x<<<(M * K / 4) / 256, 256, 0, stream>>>(x, xh);
        qgemm<true><<<(M / 128) * (N / 128), 256, 0, stream>>>(xh, wq, out, scale, M, N, K);
    } else if (ws_size >= OFF_WQ + WQ_BYTES) {
        quantize_w<<<(N * K / 4) / 256, 256, 0, stream>>>(W, wq, scale);
        qgemm<false><<<(M / 128) * (N / 128), 256, 0, stream>>>(x, wq, out, scale, M, N, K);
    } else {
        naive_qgemm<<<dim3(N / 256, M), 256, 0, stream>>>(x, W, out, scale, M);
    }
}

// Round 12
// 314.463 us; speedup vs baseline: 1.0902x; 1.0902x over previous
//
#include <hip/hip_runtime.h>
#include <cstdint>
#include <cstddef>

#define IN_F 4096
#define OUT_F 4096

typedef __attribute__((ext_vector_type(8))) short bf16x8;
typedef __attribute__((ext_vector_type(4))) float f32x4;

__device__ __forceinline__ ushort f32_bf16_rne(float f) {
    uint32_t u = __builtin_bit_cast(uint32_t, f);
    uint32_t r = (u + 0x7FFFu + ((u >> 16) & 1u)) >> 16;
    return (ushort)r;
}

__device__ __forceinline__ void gload_lds16(const void* g, void* l) {
    __builtin_amdgcn_global_load_lds(
        (const __attribute__((address_space(1))) uint32_t*)g,
        (__attribute__((address_space(3))) uint32_t*)l,
        16, 0, 0);
}

// ---------- deterministic |W| reduction (fixed order, no atomics) ----------
__global__ void reduce_abs1(const float* __restrict__ W, float* __restrict__ part) {
    __shared__ float sm[256];
    const int b = blockIdx.x, t = threadIdx.x;
    const float* p = W + (size_t)b * 4096;
    float s = 0.f;
#pragma unroll
    for (int j = 0; j < 16; ++j) s += fabsf(p[t + 256 * j]);
    sm[t] = s;
    __syncthreads();
    for (int w = 128; w > 0; w >>= 1) {
        if (t < w) sm[t] += sm[t + w];
        __syncthreads();
    }
    if (t == 0) part[b] = sm[0];
}

__global__ void reduce_abs2(const float* __restrict__ part, float* __restrict__ scale) {
    __shared__ float sm[256];
    const int t = threadIdx.x;
    float s = 0.f;
#pragma unroll
    for (int j = 0; j < 16; ++j) s += part[t + 256 * j];
    sm[t] = s;
    __syncthreads();
    for (int w = 128; w > 0; w >>= 1) {
        if (t < w) sm[t] += sm[t + w];
        __syncthreads();
    }
    if (t == 0) {
        float m = sm[0] / 16777216.0f;
        *scale = fmaxf(m, 1e-8f);
    }
}

// ---------- quantize W -> bf16 {-2,-1,0,1,2} (exact in bf16) ----------
__global__ void quantize_w(const float* __restrict__ W, ushort* __restrict__ wq,
                           const float* __restrict__ scale_p) {
    const int i = blockIdx.x * 256 + threadIdx.x;
    const float s = *scale_p;
    float4 v = ((const float4*)W)[i];
    float q0 = fminf(fmaxf(rintf(v.x / s), -2.f), 2.f);
    float q1 = fminf(fmaxf(rintf(v.y / s), -2.f), 2.f);
    float q2 = fminf(fmaxf(rintf(v.z / s), -2.f), 2.f);
    float q3 = fminf(fmaxf(rintf(v.w / s), -2.f), 2.f);
    ushort4 o;
    o.x = f32_bf16_rne(q0); o.y = f32_bf16_rne(q1);
    o.z = f32_bf16_rne(q2); o.w = f32_bf16_rne(q3);
    ((ushort4*)wq)[i] = o;
}

// ---------- cast x -> bf16 (RNE) ----------
__global__ void cast_x(const float* __restrict__ X, ushort* __restrict__ xh) {
    const int i = blockIdx.x * 256 + threadIdx.x;
    float4 v = ((const float4*)X)[i];
    ushort4 o;
    o.x = f32_bf16_rne(v.x); o.y = f32_bf16_rne(v.y);
    o.z = f32_bf16_rne(v.z); o.w = f32_bf16_rne(v.w);
    ((ushort4*)xh)[i] = o;
}

// ======= 256x256 GEMM: m201-faithful 8-phase, PLAIN barriers (R12) ==========
// C = scale * (A @ B^T).  A:[M][K] bf16, B:[N][K] bf16 (both K-contiguous).
// 512 threads = 8 waves (2M x 4N); per-wave 128x64 output (acc[8][4], AGPR).
// LDS 128 KiB: 2 K-tile buffers x {A0,A1,B0,B1} 16-KiB halves, XOR-swizzled
// (byte ^= (r&7)<<4) via pre-swizzled global source + swizzled ds_read.
//
// R12 change: ALL barriers are plain __builtin_amdgcn_s_barrier() and ALL
// waitcnts are clobber-free asm.  R3-R11 wrapped every barrier in a
// ::: "memory" clobber, which forbids the compiler from letting plain LDS
// loads drain across the phase boundary / float against the MFMA cluster --
// each phase serialized {reads}->{MFMA}, giving the measured 2483+2304
// ~= 4900 cyc/K-tile SUM.  m201 (62% MfmaUtil, same 1-block/CU geometry)
// uses plain barriers; reads issued pre-barrier complete during barrier-wait
// and under co-wave MFMA.
//
// Clobber-free safety: every plain read targets tile kt, which is FULLY
// vmcnt-confirmed before the iteration starts (stream below), so upward
// hoisting within the iteration cannot read unpublished data; stage
// intrinsics / waitcnt asm / barriers are side-effecting and keep their
// mutual order.
//
// Phases (reads 12/8/4/0, m201 layout):
//  P1: read b01+a0 | stage B0(kt+1,nxt) | bar | lgkm0 | Q00 | bar
//  P2: read a1     | stage B1(kt+1,nxt) | bar | lgkm0 | Q10 | bar
//  P3: read b23    | stage A0(kt+2,cur) | bar | lgkm0 | Q01 | bar
//  P4:             | stage A1(kt+2,cur) | vmcnt(4) | bar | lgkm0 | Q11 | bar
// WAR: every stage lands >=1 lgkm-drained barrier after its region's last
// read (B(kt-1) read P3 -> staged next-P1; A(kt) read P2 -> staged P3/P4).
// RAW: vmcnt(4)@P4 confirms through B1(kt+1) (leaves A(kt+2)'s 4 loads), so
// tile kt+1 is fully landed at its first read.  Prologue: tile0 all + tile1
// A halves (6 halves), vmcnt(4).  Tail: kt>=NT-2 -> vmcnt(0) (stages stop
// pushing the counter; R6 lesson).
#define BK 64
#define BUF_BYTES 65536

__global__ __launch_bounds__(512, 2) void qgemm256(
        const ushort* __restrict__ Ab, const ushort* __restrict__ Bq,
        float* __restrict__ C, const float* __restrict__ scale_p,
        int M, int N, int K) {
    extern __shared__ __align__(16) char smem[];

    const int t = threadIdx.x;
    const int lane = t & 63;
    const int w = t >> 6;
    const int wr = w >> 2;   // 0..1 (M half)
    const int wc = w & 3;    // 0..3 (N quarter)
    const int bh = wc >> 1;  // B half

    // ---- 2D XCD-aware supertiling (validated R7: FETCH 541->197 MB) ----
    const int MT = M >> 8;
    const int NTiles = N >> 8;
    int mt, nt;
    if (MT == 32 && NTiles == 16 && gridDim.x == 512) {
        const int x = blockIdx.x & 7;
        const int j = blockIdx.x >> 3;
        const int jr = j & 31;
        const int r = j >> 5;
        mt = (x & 3) * 8 + (jr & 7);
        nt = r * 8 + (x >> 2) * 4 + (jr >> 3);
    } else {
        const int nwg = gridDim.x;
        int wg = blockIdx.x;
        if ((nwg & 7) == 0) wg = (wg & 7) * (nwg >> 3) + (wg >> 3);
        mt = wg % MT; nt = wg / MT;
    }
    const int m0 = mt << 8;
    const int n0 = nt << 8;

    const int NT = K / BK;

    // per-lane ds_read byte offsets within a 16-KiB half (add frag*2048)
    int pre[2];
#pragma unroll
    for (int ks = 0; ks < 2; ++ks)
        pre[ks] = (lane & 15) * 128 +
                  (((ks * 64) + ((lane >> 4) * 16)) ^ ((lane & 7) << 4));

    // ---- incrementing stage pointers (swizzled source, linear LDS dest) ----
    const int rowA = t >> 3;                                // 0..63
    const int colsw = ((t & 7) ^ ((t >> 3) & 7)) << 3;      // swizzled col (elems)
    const ushort* gA0 = Ab + (size_t)(m0 + rowA) * K + colsw;
    const ushort* gA1 = Ab + (size_t)(m0 + 128 + rowA) * K + colsw;
    const ushort* gB0 = Bq + (size_t)(n0 + rowA) * K + colsw;
    const ushort* gB1 = Bq + (size_t)(n0 + 128 + rowA) * K + colsw;
    const size_t jrow = (size_t)64 * K;                     // +64 rows
    char* lb = smem + t * 16;

    // one half-tile each (2 gload_lds16), advancing its pointer one K-tile
    auto stA0 = [&](uint32_t par) {
        gload_lds16(gA0,        lb + par);
        gload_lds16(gA0 + jrow, lb + par + 8192);
        gA0 += 64;
    };
    auto stA1 = [&](uint32_t par) {
        gload_lds16(gA1,        lb + par + 16384);
        gload_lds16(gA1 + jrow, lb + par + 24576);
        gA1 += 64;
    };
    auto stB0 = [&](uint32_t par) {
        gload_lds16(gB0,        lb + par + 32768);
        gload_lds16(gB0 + jrow, lb + par + 40960);
        gB0 += 64;
    };
    auto stB1 = [&](uint32_t par) {
        gload_lds16(gB1,        lb + par + 49152);
        gload_lds16(gB1 + jrow, lb + par + 57344);
        gB1 += 64;
    };

    const char* aBbase = smem + wr * 16384;                        // wave's A half
    const char* bBbase = smem + 32768 + bh * 16384 + (wc & 1) * 8192;  // wave's B strip

    f32x4 acc[8][4];
#pragma unroll
    for (int m = 0; m < 8; ++m)
#pragma unroll
        for (int n = 0; n < 4; ++n) acc[m][n] = (f32x4){0.f, 0.f, 0.f, 0.f};

    // ---- prologue: tile0 all 4 halves + tile1 A halves; vmcnt(4) ----
    stB0(0); stB1(0); stA0(0); stA1(0);
    stA0(BUF_BYTES); stA1(BUF_BYTES);
    asm volatile("s_waitcnt vmcnt(4)");  // tile0 confirmed; A(1) in flight
    __builtin_amdgcn_s_barrier();

    for (int kt = 0; kt < NT; ++kt) {
        const uint32_t cur = (uint32_t)(kt & 1) * BUF_BYTES;
        const uint32_t nxt = cur ^ BUF_BYTES;
        const char* aB = aBbase + cur;
        const char* bB = bBbase + cur;

        bf16x8 a0[4][2], a1[4][2], b01[2][2], b23[2][2];

        // -------- P1: read b01 + a0; stage B0(kt+1); Q00 --------
#pragma unroll
        for (int n = 0; n < 2; ++n)
#pragma unroll
            for (int ks = 0; ks < 2; ++ks)
                b01[n][ks] = *(const bf16x8*)(bB + n * 2048 + pre[ks]);
#pragma unroll
        for (int m = 0; m < 4; ++m)
#pragma unroll
            for (int ks = 0; ks < 2; ++ks)
                a0[m][ks] = *(const bf16x8*)(aB + m * 2048 + pre[ks]);
        if (kt + 1 < NT) stB0(nxt);
        __builtin_amdgcn_s_barrier();
        asm volatile("s_waitcnt lgkmcnt(0)");
        __builtin_amdgcn_s_setprio(1);
#pragma unroll
        for (int m = 0; m < 4; ++m)
#pragma unroll
            for (int n = 0; n < 2; ++n)
#pragma unroll
                for (int ks = 0; ks < 2; ++ks)
                    acc[m][n] = __builtin_amdgcn_mfma_f32_16x16x32_bf16(
                        a0[m][ks], b01[n][ks], acc[m][n], 0, 0, 0);
        __builtin_amdgcn_s_setprio(0);
        __builtin_amdgcn_s_barrier();

        // -------- P2: read a1; stage B1(kt+1); Q10 --------
#pragma unroll
        for (int m = 0; m < 4; ++m)
#pragma unroll
            for (int ks = 0; ks < 2; ++ks)
                a1[m][ks] = *(const bf16x8*)(aB + (m + 4) * 2048 + pre[ks]);
        if (kt + 1 < NT) stB1(nxt);
        __builtin_amdgcn_s_barrier();
        asm volatile("s_waitcnt lgkmcnt(0)");
        __builtin_amdgcn_s_setprio(1);
#pragma unroll
        for (int m = 0; m < 4; ++m)
#pragma unroll
            for (int n = 0; n < 2; ++n)
#pragma unroll
                for (int ks = 0; ks < 2; ++ks)
                    acc[m + 4][n] = __builtin_amdgcn_mfma_f32_16x16x32_bf16(
                        a1[m][ks], b01[n][ks], acc[m + 4][n], 0, 0, 0);
        __builtin_amdgcn_s_setprio(0);
        __builtin_amdgcn_s_barrier();

        // -------- P3: read b23; stage A0(kt+2); Q01 --------
#pragma unroll
        for (int n = 0; n < 2; ++n)
#pragma unroll
            for (int ks = 0; ks < 2; ++ks)
                b23[n][ks] = *(const bf16x8*)(bB + (n + 2) * 2048 + pre[ks]);
        if (kt + 2 < NT) stA0(cur);
        __builtin_amdgcn_s_barrier();
        asm volatile("s_waitcnt lgkmcnt(0)");
        __builtin_amdgcn_s_setprio(1);
#pragma unroll
        for (int m = 0; m < 4; ++m)
#pragma unroll
            for (int n = 0; n < 2; ++n)
#pragma unroll
                for (int ks = 0; ks < 2; ++ks)
                    acc[m][n + 2] = __builtin_amdgcn_mfma_f32_16x16x32_bf16(
                        a0[m][ks], b23[n][ks], acc[m][n + 2], 0, 0, 0);
        __builtin_amdgcn_s_setprio(0);
        __builtin_amdgcn_s_barrier();

        // -------- P4: stage A1(kt+2); boundary vmcnt; Q11 --------
        if (kt + 2 < NT) stA1(cur);
        if (kt < NT - 2) {
            asm volatile("s_waitcnt vmcnt(4)");  // confirms through B1(kt+1)
        } else {
            asm volatile("s_waitcnt vmcnt(0)");  // tail drain (R6 lesson)
        }
        __builtin_amdgcn_s_barrier();
        asm volatile("s_waitcnt lgkmcnt(0)");
        __builtin_amdgcn_s_setprio(1);
#pragma unroll
        for (int m = 0; m < 4; ++m)
#pragma unroll
            for (int n = 0; n < 2; ++n)
#pragma unroll
                for (int ks = 0; ks < 2; ++ks)
                    acc[m + 4][n + 2] = __builtin_amdgcn_mfma_f32_16x16x32_bf16(
                        a1[m][ks], b23[n][ks], acc[m + 4][n + 2], 0, 0, 0);
        __builtin_amdgcn_s_setprio(0);
        __builtin_amdgcn_s_barrier();
    }

    const float s = *scale_p;
#pragma unroll
    for (int m = 0; m < 8; ++m)
#pragma unroll
        for (int n = 0; n < 4; ++n) {
            const int col = n0 + wc * 64 + n * 16 + (lane & 15);
            const int rbase = m0 + wr * 128 + m * 16 + ((lane >> 4) << 2);
#pragma unroll
            for (int j = 0; j < 4; ++j)
                C[(size_t)(rbase + j) * N + col] = s * acc[m][n][j];
        }
}

// ---------- 128^2 fallback (validated round 2) ----------
template <bool ABF16>
__global__ __launch_bounds__(256) void qgemm(const void* __restrict__ Aptr,
                                             const ushort* __restrict__ Bq,
                                             float* __restrict__ C,
                                             const float* __restrict__ scale_p,
                                             int M, int N, int K) {
    __shared__ __align__(16) ushort sA[128 * 64];
    __shared__ __align__(16) ushort sB[128 * 64];

    const int t = threadIdx.x;
    const int lane = t & 63;
    const int w = t >> 6;
    const int wr = w >> 1, wc = w & 1;

    const int nwg = gridDim.x;
    int wg = blockIdx.x;
    if ((nwg & 7) == 0) wg = (wg & 7) * (nwg >> 3) + (wg >> 3);
    const int MT = M >> 7;
    const int mt = wg % MT;
    const int nt = wg / MT;
    const int m0 = mt * 128, n0 = nt * 128;

    const ushort* Ab = (const ushort*)Aptr;
    const float* Af = (const float*)Aptr;

    f32x4 zero = {0.f, 0.f, 0.f, 0.f};
    f32x4 acc[4][4];
#pragma unroll
    for (int m = 0; m < 4; ++m)
#pragma unroll
        for (int n = 0; n < 4; ++n) acc[m][n] = zero;

    for (int k0 = 0; k0 < K; k0 += 64) {
#pragma unroll
        for (int i = 0; i < 4; ++i) {
            int e = i * 2048 + t * 8;
            int r = e >> 6, c8 = (e >> 3) & 7;
            int srcc = (c8 ^ (r & 7)) * 8;
            gload_lds16(Bq + (size_t)(n0 + r) * K + (k0 + srcc), &sB[e]);
        }
        if constexpr (ABF16) {
#pragma unroll
            for (int i = 0; i < 4; ++i) {
                int e = i * 2048 + t * 8;
                int r = e >> 6, c8 = (e >> 3) & 7;
                int srcc = (c8 ^ (r & 7)) * 8;
                gload_lds16(Ab + (size_t)(m0 + r) * K + (k0 + srcc), &sA[e]);
            }
        } else {
#pragma unroll
            for (int i = 0; i < 4; ++i) {
                int e = i * 2048 + t * 8;
                int r = e >> 6, c = e & 63;
                const float* src = Af + (size_t)(m0 + r) * K + (k0 + c);
                float4 v0 = *(const float4*)src;
                float4 v1 = *(const float4*)(src + 4);
                bf16x8 pk;
                pk[0] = (short)f32_bf16_rne(v0.x); pk[1] = (short)f32_bf16_rne(v0.y);
                pk[2] = (short)f32_bf16_rne(v0.z); pk[3] = (short)f32_bf16_rne(v0.w);
                pk[4] = (short)f32_bf16_rne(v1.x); pk[5] = (short)f32_bf16_rne(v1.y);
                pk[6] = (short)f32_bf16_rne(v1.z); pk[7] = (short)f32_bf16_rne(v1.w);
                int byte = (r * 128 + c * 2) ^ ((r & 7) << 4);
                *(bf16x8*)((char*)sA + byte) = pk;
            }
        }
        __syncthreads();

#pragma unroll
        for (int ks = 0; ks < 2; ++ks) {
            const int kk = ks * 32 + ((lane >> 4) << 3);
            bf16x8 afr[4], bfr[4];
#pragma unroll
            for (int m = 0; m < 4; ++m) {
                int r = wr * 64 + m * 16 + (lane & 15);
                int byte = (r * 128 + kk * 2) ^ ((r & 7) << 4);
                afr[m] = *(const bf16x8*)((const char*)sA + byte);
            }
#pragma unroll
            for (int n = 0; n < 4; ++n) {
                int r = wc * 64 + n * 16 + (lane & 15);
                int byte = (r * 128 + kk * 2) ^ ((r & 7) << 4);
                bfr[n] = *(const bf16x8*)((const char*)sB + byte);
            }
#pragma unroll
            for (int m = 0; m < 4; ++m)
#pragma unroll
                for (int n = 0; n < 4; ++n)
                    acc[m][n] = __builtin_amdgcn_mfma_f32_16x16x32_bf16(
                        afr[m], bfr[n], acc[m][n], 0, 0, 0);
        }
        __syncthreads();
    }

    const float s = *scale_p;
#pragma unroll
    for (int m = 0; m < 4; ++m)
#pragma unroll
        for (int n = 0; n < 4; ++n) {
            const int col = n0 + wc * 64 + n * 16 + (lane & 15);
            const int rbase = m0 + wr * 64 + m * 16 + ((lane >> 4) << 2);
#pragma unroll
            for (int j = 0; j < 4; ++j)
                C[(size_t)(rbase + j) * N + col] = s * acc[m][n][j];
        }
}

// ---------- last-resort naive path ----------
__global__ void naive_qgemm(const float* __restrict__ X, const float* __restrict__ W,
                            float* __restrict__ out, const float* __restrict__ scale_p,
                            int M) {
    const int col = blockIdx.x * 256 + threadIdx.x;
    const int row = blockIdx.y;
    const float s = *scale_p;
    const float inv = 1.0f / s;
    const float* xr = X + (size_t)row * IN_F;
    const float* wrow = W + (size_t)col * IN_F;
    float acc = 0.f;
    for (int k = 0; k < IN_F; ++k) {
        float q = fminf(fmaxf(rintf(wrow[k] * inv), -2.f), 2.f);
        acc += xr[k] * q;
    }
    out[(size_t)row * OUT_F + col] = acc * s;
}

extern "C" void kernel_launch(void* const* d_in, const int* in_sizes, int n_in,
                              void* d_out, int out_size, void* d_ws, size_t ws_size,
                              hipStream_t stream) {
    const float* x = (const float*)d_in[0];
    const float* W = (const float*)d_in[1];
    float* out = (float*)d_out;
    const int M = in_sizes[0] / IN_F;  // 8192
    const int K = IN_F, N = OUT_F;

    char* ws = (char*)d_ws;
    const size_t OFF_PART = 512;
    const size_t OFF_WQ = OFF_PART + 4096 * sizeof(float);
    const size_t WQ_BYTES = (size_t)N * K * sizeof(ushort);
    const size_t OFF_XH = OFF_WQ + WQ_BYTES;
    const size_t XH_BYTES = (size_t)M * K * sizeof(ushort);
    float* scale = (float*)(ws + 0);
    float* part = (float*)(ws + OFF_PART);
    ushort* wq = (ushort*)(ws + OFF_WQ);
    ushort* xh = (ushort*)(ws + OFF_XH);

    if (ws_size < OFF_WQ) return;

    reduce_abs1<<<4096, 256, 0, stream>>>(W, part);
    reduce_abs2<<<1, 256, 0, stream>>>(part, scale);

    if (ws_size >= OFF_XH + XH_BYTES && (M % 256) == 0 && (N % 256) == 0) {
        quantize_w<<<(N * K / 4) / 256, 256, 0, stream>>>(W, wq, scale);
        cast_x<<<(M * K / 4) / 256, 256, 0, stream>>>(x, xh);
        (void)hipFuncSetAttribute((const void*)qgemm256,
                                  hipFuncAttributeMaxDynamicSharedMemorySize,
                                  131072);
        qgemm256<<<(M / 256) * (N / 256), 512, 131072, stream>>>(
            xh, wq, out, scale, M, N, K);
    } else if (ws_size >= OFF_XH + XH_BYTES) {
        quantize_w<<<(N * K / 4) / 256, 256, 0, stream>>>(W, wq, scale);
        cast_x<<<(M * K / 4) / 256, 256, 0, stream>>>(x, xh);
        qgemm<true><<<(M / 128) * (N / 128), 256, 0, stream>>>(xh, wq, out, scale, M, N, K);
    } else if (ws_size >= OFF_WQ + WQ_BYTES) {
        quantize_w<<<(N * K / 4) / 256, 256, 0, stream>>>(W, wq, scale);
        qgemm<false><<<(M / 128) * (N / 128), 256, 0, stream>>>(x, wq, out, scale, M, N, K);
    } else {
        naive_qgemm<<<dim3(N / 256, M), 256, 0, stream>>>(x, W, out, scale, M);
    }
}

// Round 13
// 307.410 us; speedup vs baseline: 1.1152x; 1.0229x over previous
//
#include <hip/hip_runtime.h>
#include <cstdint>
#include <cstddef>

#define IN_F 4096
#define OUT_F 4096

typedef __attribute__((ext_vector_type(8))) short bf16x8;
typedef __attribute__((ext_vector_type(4))) float f32x4;

__device__ __forceinline__ ushort f32_bf16_rne(float f) {
    uint32_t u = __builtin_bit_cast(uint32_t, f);
    uint32_t r = (u + 0x7FFFu + ((u >> 16) & 1u)) >> 16;
    return (ushort)r;
}

__device__ __forceinline__ void gload_lds16(const void* g, void* l) {
    __builtin_amdgcn_global_load_lds(
        (const __attribute__((address_space(1))) uint32_t*)g,
        (__attribute__((address_space(3))) uint32_t*)l,
        16, 0, 0);
}

// ---------- deterministic |W| reduction (fixed order, no atomics) ----------
__global__ void reduce_abs1(const float* __restrict__ W, float* __restrict__ part) {
    __shared__ float sm[256];
    const int b = blockIdx.x, t = threadIdx.x;
    const float* p = W + (size_t)b * 4096;
    float s = 0.f;
#pragma unroll
    for (int j = 0; j < 16; ++j) s += fabsf(p[t + 256 * j]);
    sm[t] = s;
    __syncthreads();
    for (int w = 128; w > 0; w >>= 1) {
        if (t < w) sm[t] += sm[t + w];
        __syncthreads();
    }
    if (t == 0) part[b] = sm[0];
}

__global__ void reduce_abs2(const float* __restrict__ part, float* __restrict__ scale) {
    __shared__ float sm[256];
    const int t = threadIdx.x;
    float s = 0.f;
#pragma unroll
    for (int j = 0; j < 16; ++j) s += part[t + 256 * j];
    sm[t] = s;
    __syncthreads();
    for (int w = 128; w > 0; w >>= 1) {
        if (t < w) sm[t] += sm[t + w];
        __syncthreads();
    }
    if (t == 0) {
        float m = sm[0] / 16777216.0f;
        *scale = fmaxf(m, 1e-8f);
    }
}

// ---------- quantize W -> bf16 {-2,-1,0,1,2} (exact in bf16) ----------
__global__ void quantize_w(const float* __restrict__ W, ushort* __restrict__ wq,
                           const float* __restrict__ scale_p) {
    const int i = blockIdx.x * 256 + threadIdx.x;
    const float s = *scale_p;
    float4 v = ((const float4*)W)[i];
    float q0 = fminf(fmaxf(rintf(v.x / s), -2.f), 2.f);
    float q1 = fminf(fmaxf(rintf(v.y / s), -2.f), 2.f);
    float q2 = fminf(fmaxf(rintf(v.z / s), -2.f), 2.f);
    float q3 = fminf(fmaxf(rintf(v.w / s), -2.f), 2.f);
    ushort4 o;
    o.x = f32_bf16_rne(q0); o.y = f32_bf16_rne(q1);
    o.z = f32_bf16_rne(q2); o.w = f32_bf16_rne(q3);
    ((ushort4*)wq)[i] = o;
}

// ---------- cast x -> bf16 (RNE) ----------
__global__ void cast_x(const float* __restrict__ X, ushort* __restrict__ xh) {
    const int i = blockIdx.x * 256 + threadIdx.x;
    float4 v = ((const float4*)X)[i];
    ushort4 o;
    o.x = f32_bf16_rne(v.x); o.y = f32_bf16_rne(v.y);
    o.z = f32_bf16_rne(v.z); o.w = f32_bf16_rne(v.w);
    ((ushort4*)xh)[i] = o;
}

// ===== 256x256 GEMM: one-phase-ahead read pipeline (R13) =====================
// C = scale * (A @ B^T).  A:[M][K] bf16, B:[N][K] bf16 (both K-contiguous).
// 512 threads = 8 waves (2M x 4N); per-wave 128x64 output (acc[8][4], AGPR).
// LDS 128 KiB: 2 K-tile buffers x {A0,A1,B0,B1} 16-KiB halves, XOR-swizzled
// (byte ^= (r&7)<<4) via pre-swizzled global source + swizzled ds_read.
//
// R13 mechanism (counted-lgkm analog of T4): every ds_read burst is issued
// >= 1 full MFMA cluster (~620 cyc) BEFORE its consume-wait, so the 8-wave
// LDS service (<=400 cyc/burst) hides under MFMA by construction.  R3-R12
// all drained each burst right before its consumer (lgkmcnt(0) or the
// compiler's first-consumer wait) -> LDS time fully exposed -> 47% plateau.
//
// Per K-tile (quadrants Q00:a0xb01, Q10:a1xb01, Q01:a0xb23, Q11:a1xb23):
//  P1: issue a1(kt)            | Q00   (a0,b01 read last tile P3/P4)
//  P2: issue b23(kt)           | Q10   | vmcnt(0)+bar  -> publish tile kt+1
//  P3: issue b01(kt+1, nxt)    | Q01
//  P4: issue a0(kt+1, nxt) | WAR-bar | stage(kt+2 -> cur) | Q11 (no wait)
// Register WAR: each frag re-read one phase after its last consumer.
// LDS WAR: at P4's barrier every wave's tile-kt reads are data-complete
// (its own Q01 consumed b23/a0).  RAW: nxt-buf reads only after the publish
// bar (R12 precedent: loads don't cross s_barrier).  Tail: haveNext guards;
// sched_barrier(0) fences pin read-issue placement (rule #18).
#define BK 64
#define BUF_BYTES 65536

__global__ __launch_bounds__(512, 2) void qgemm256(
        const ushort* __restrict__ Ab, const ushort* __restrict__ Bq,
        float* __restrict__ C, const float* __restrict__ scale_p,
        int M, int N, int K) {
    extern __shared__ __align__(16) char smem[];

    const int t = threadIdx.x;
    const int lane = t & 63;
    const int w = t >> 6;
    const int wr = w >> 2;   // 0..1 (M half)
    const int wc = w & 3;    // 0..3 (N quarter)
    const int bh = wc >> 1;  // B half

    // ---- 2D XCD-aware supertiling (validated R7: FETCH 541->197 MB) ----
    const int MT = M >> 8;
    const int NTiles = N >> 8;
    int mt, nt;
    if (MT == 32 && NTiles == 16 && gridDim.x == 512) {
        const int x = blockIdx.x & 7;
        const int j = blockIdx.x >> 3;
        const int jr = j & 31;
        const int r = j >> 5;
        mt = (x & 3) * 8 + (jr & 7);
        nt = r * 8 + (x >> 2) * 4 + (jr >> 3);
    } else {
        const int nwg = gridDim.x;
        int wg = blockIdx.x;
        if ((nwg & 7) == 0) wg = (wg & 7) * (nwg >> 3) + (wg >> 3);
        mt = wg % MT; nt = wg / MT;
    }
    const int m0 = mt << 8;
    const int n0 = nt << 8;

    const int NT = K / BK;

    // per-lane ds_read byte offsets within a 16-KiB half (add frag*2048)
    int pre[2];
#pragma unroll
    for (int ks = 0; ks < 2; ++ks)
        pre[ks] = (lane & 15) * 128 +
                  (((ks * 64) + ((lane >> 4) * 16)) ^ ((lane & 7) << 4));

    // ---- incrementing stage pointers (swizzled source, linear LDS dest) ----
    const int rowA = t >> 3;                                // 0..63
    const int colsw = ((t & 7) ^ ((t >> 3) & 7)) << 3;      // swizzled col (elems)
    const ushort* gA0 = Ab + (size_t)(m0 + rowA) * K + colsw;
    const ushort* gA1 = Ab + (size_t)(m0 + 128 + rowA) * K + colsw;
    const ushort* gB0 = Bq + (size_t)(n0 + rowA) * K + colsw;
    const ushort* gB1 = Bq + (size_t)(n0 + 128 + rowA) * K + colsw;
    const size_t jrow = (size_t)64 * K;                     // +64 rows
    char* lb = smem + t * 16;

    auto st = [&](uint32_t par) {   // full K-tile (all 4 halves, 8 instr)
        gload_lds16(gA0,        lb + par);
        gload_lds16(gA0 + jrow, lb + par + 8192);
        gload_lds16(gA1,        lb + par + 16384);
        gload_lds16(gA1 + jrow, lb + par + 24576);
        gload_lds16(gB0,        lb + par + 32768);
        gload_lds16(gB0 + jrow, lb + par + 40960);
        gload_lds16(gB1,        lb + par + 49152);
        gload_lds16(gB1 + jrow, lb + par + 57344);
        gA0 += 64; gA1 += 64; gB0 += 64; gB1 += 64;
    };

    const char* aBbase = smem + wr * 16384;                        // wave's A half
    const char* bBbase = smem + 32768 + bh * 16384 + (wc & 1) * 8192;  // wave's B strip

    f32x4 acc[8][4];
#pragma unroll
    for (int m = 0; m < 8; ++m)
#pragma unroll
        for (int n = 0; n < 4; ++n) acc[m][n] = (f32x4){0.f, 0.f, 0.f, 0.f};

    bf16x8 a0[4][2], a1[4][2], b01[2][2], b23[2][2];

    // ---- prologue: stage tiles 0,1; publish tile 0; preload a0,b01(tile 0) --
    st(0);
    st(BUF_BYTES);
    asm volatile("s_waitcnt vmcnt(8)" ::: "memory");  // tile 0 landed
    __builtin_amdgcn_s_barrier();                     // publish tile 0
    __builtin_amdgcn_sched_barrier(0);
#pragma unroll
    for (int n = 0; n < 2; ++n)
#pragma unroll
        for (int ks = 0; ks < 2; ++ks)
            b01[n][ks] = *(const bf16x8*)(bBbase + n * 2048 + pre[ks]);
#pragma unroll
    for (int m = 0; m < 4; ++m)
#pragma unroll
        for (int ks = 0; ks < 2; ++ks)
            a0[m][ks] = *(const bf16x8*)(aBbase + m * 2048 + pre[ks]);

    for (int kt = 0; kt < NT; ++kt) {
        const uint32_t cur = (uint32_t)(kt & 1) * BUF_BYTES;
        const uint32_t nxt = cur ^ BUF_BYTES;
        const char* aB = aBbase + cur;
        const char* bB = bBbase + cur;
        const char* aBn = aBbase + nxt;
        const char* bBn = bBbase + nxt;
        const bool haveNext = (kt + 1 < NT);

        // ---- P1: issue a1(kt); MFMA Q00 ----
#pragma unroll
        for (int m = 0; m < 4; ++m)
#pragma unroll
            for (int ks = 0; ks < 2; ++ks)
                a1[m][ks] = *(const bf16x8*)(aB + (m + 4) * 2048 + pre[ks]);
        __builtin_amdgcn_sched_barrier(0);
        __builtin_amdgcn_s_setprio(1);
#pragma unroll
        for (int m = 0; m < 4; ++m)
#pragma unroll
            for (int n = 0; n < 2; ++n)
#pragma unroll
                for (int ks = 0; ks < 2; ++ks)
                    acc[m][n] = __builtin_amdgcn_mfma_f32_16x16x32_bf16(
                        a0[m][ks], b01[n][ks], acc[m][n], 0, 0, 0);
        __builtin_amdgcn_s_setprio(0);
        __builtin_amdgcn_sched_barrier(0);

        // ---- P2: issue b23(kt); MFMA Q10; publish tile kt+1 ----
#pragma unroll
        for (int n = 0; n < 2; ++n)
#pragma unroll
            for (int ks = 0; ks < 2; ++ks)
                b23[n][ks] = *(const bf16x8*)(bB + (n + 2) * 2048 + pre[ks]);
        __builtin_amdgcn_sched_barrier(0);
        __builtin_amdgcn_s_setprio(1);
#pragma unroll
        for (int m = 0; m < 4; ++m)
#pragma unroll
            for (int n = 0; n < 2; ++n)
#pragma unroll
                for (int ks = 0; ks < 2; ++ks)
                    acc[m + 4][n] = __builtin_amdgcn_mfma_f32_16x16x32_bf16(
                        a1[m][ks], b01[n][ks], acc[m + 4][n], 0, 0, 0);
        __builtin_amdgcn_s_setprio(0);
        __builtin_amdgcn_sched_barrier(0);
        if (haveNext) {
            asm volatile("s_waitcnt vmcnt(0)" ::: "memory");  // stage(kt+1) done
            __builtin_amdgcn_s_barrier();                     // publish tile kt+1
            __builtin_amdgcn_sched_barrier(0);
        }

        // ---- P3: issue b01(kt+1, nxt); MFMA Q01 ----
        if (haveNext) {
#pragma unroll
            for (int n = 0; n < 2; ++n)
#pragma unroll
                for (int ks = 0; ks < 2; ++ks)
                    b01[n][ks] = *(const bf16x8*)(bBn + n * 2048 + pre[ks]);
        }
        __builtin_amdgcn_sched_barrier(0);
        __builtin_amdgcn_s_setprio(1);
#pragma unroll
        for (int m = 0; m < 4; ++m)
#pragma unroll
            for (int n = 0; n < 2; ++n)
#pragma unroll
                for (int ks = 0; ks < 2; ++ks)
                    acc[m][n + 2] = __builtin_amdgcn_mfma_f32_16x16x32_bf16(
                        a0[m][ks], b23[n][ks], acc[m][n + 2], 0, 0, 0);
        __builtin_amdgcn_s_setprio(0);
        __builtin_amdgcn_sched_barrier(0);

        // ---- P4: issue a0(kt+1, nxt); WAR-bar; stage(kt+2); MFMA Q11 ----
        if (haveNext) {
#pragma unroll
            for (int m = 0; m < 4; ++m)
#pragma unroll
                for (int ks = 0; ks < 2; ++ks)
                    a0[m][ks] = *(const bf16x8*)(aBn + m * 2048 + pre[ks]);
        }
        __builtin_amdgcn_sched_barrier(0);
        __builtin_amdgcn_s_barrier();   // all waves' tile-kt reads complete
        __builtin_amdgcn_sched_barrier(0);
        if (kt + 2 < NT) st(cur);       // stage tile kt+2 over tile kt
        __builtin_amdgcn_s_setprio(1);
#pragma unroll
        for (int m = 0; m < 4; ++m)
#pragma unroll
            for (int n = 0; n < 2; ++n)
#pragma unroll
                for (int ks = 0; ks < 2; ++ks)
                    acc[m + 4][n + 2] = __builtin_amdgcn_mfma_f32_16x16x32_bf16(
                        a1[m][ks], b23[n][ks], acc[m + 4][n + 2], 0, 0, 0);
        __builtin_amdgcn_s_setprio(0);
        __builtin_amdgcn_sched_barrier(0);
    }

    const float s = *scale_p;
#pragma unroll
    for (int m = 0; m < 8; ++m)
#pragma unroll
        for (int n = 0; n < 4; ++n) {
            const int col = n0 + wc * 64 + n * 16 + (lane & 15);
            const int rbase = m0 + wr * 128 + m * 16 + ((lane >> 4) << 2);
#pragma unroll
            for (int j = 0; j < 4; ++j)
                C[(size_t)(rbase + j) * N + col] = s * acc[m][n][j];
        }
}

// ---------- 128^2 fallback (validated round 2) ----------
template <bool ABF16>
__global__ __launch_bounds__(256) void qgemm(const void* __restrict__ Aptr,
                                             const ushort* __restrict__ Bq,
                                             float* __restrict__ C,
                                             const float* __restrict__ scale_p,
                                             int M, int N, int K) {
    __shared__ __align__(16) ushort sA[128 * 64];
    __shared__ __align__(16) ushort sB[128 * 64];

    const int t = threadIdx.x;
    const int lane = t & 63;
    const int w = t >> 6;
    const int wr = w >> 1, wc = w & 1;

    const int nwg = gridDim.x;
    int wg = blockIdx.x;
    if ((nwg & 7) == 0) wg = (wg & 7) * (nwg >> 3) + (wg >> 3);
    const int MT = M >> 7;
    const int mt = wg % MT;
    const int nt = wg / MT;
    const int m0 = mt * 128, n0 = nt * 128;

    const ushort* Ab = (const ushort*)Aptr;
    const float* Af = (const float*)Aptr;

    f32x4 zero = {0.f, 0.f, 0.f, 0.f};
    f32x4 acc[4][4];
#pragma unroll
    for (int m = 0; m < 4; ++m)
#pragma unroll
        for (int n = 0; n < 4; ++n) acc[m][n] = zero;

    for (int k0 = 0; k0 < K; k0 += 64) {
#pragma unroll
        for (int i = 0; i < 4; ++i) {
            int e = i * 2048 + t * 8;
            int r = e >> 6, c8 = (e >> 3) & 7;
            int srcc = (c8 ^ (r & 7)) * 8;
            gload_lds16(Bq + (size_t)(n0 + r) * K + (k0 + srcc), &sB[e]);
        }
        if constexpr (ABF16) {
#pragma unroll
            for (int i = 0; i < 4; ++i) {
                int e = i * 2048 + t * 8;
                int r = e >> 6, c8 = (e >> 3) & 7;
                int srcc = (c8 ^ (r & 7)) * 8;
                gload_lds16(Ab + (size_t)(m0 + r) * K + (k0 + srcc), &sA[e]);
            }
        } else {
#pragma unroll
            for (int i = 0; i < 4; ++i) {
                int e = i * 2048 + t * 8;
                int r = e >> 6, c = e & 63;
                const float* src = Af + (size_t)(m0 + r) * K + (k0 + c);
                float4 v0 = *(const float4*)src;
                float4 v1 = *(const float4*)(src + 4);
                bf16x8 pk;
                pk[0] = (short)f32_bf16_rne(v0.x); pk[1] = (short)f32_bf16_rne(v0.y);
                pk[2] = (short)f32_bf16_rne(v0.z); pk[3] = (short)f32_bf16_rne(v0.w);
                pk[4] = (short)f32_bf16_rne(v1.x); pk[5] = (short)f32_bf16_rne(v1.y);
                pk[6] = (short)f32_bf16_rne(v1.z); pk[7] = (short)f32_bf16_rne(v1.w);
                int byte = (r * 128 + c * 2) ^ ((r & 7) << 4);
                *(bf16x8*)((char*)sA + byte) = pk;
            }
        }
        __syncthreads();

#pragma unroll
        for (int ks = 0; ks < 2; ++ks) {
            const int kk = ks * 32 + ((lane >> 4) << 3);
            bf16x8 afr[4], bfr[4];
#pragma unroll
            for (int m = 0; m < 4; ++m) {
                int r = wr * 64 + m * 16 + (lane & 15);
                int byte = (r * 128 + kk * 2) ^ ((r & 7) << 4);
                afr[m] = *(const bf16x8*)((const char*)sA + byte);
            }
#pragma unroll
            for (int n = 0; n < 4; ++n) {
                int r = wc * 64 + n * 16 + (lane & 15);
                int byte = (r * 128 + kk * 2) ^ ((r & 7) << 4);
                bfr[n] = *(const bf16x8*)((const char*)sB + byte);
            }
#pragma unroll
            for (int m = 0; m < 4; ++m)
#pragma unroll
                for (int n = 0; n < 4; ++n)
                    acc[m][n] = __builtin_amdgcn_mfma_f32_16x16x32_bf16(
                        afr[m], bfr[n], acc[m][n], 0, 0, 0);
        }
        __syncthreads();
    }

    const float s = *scale_p;
#pragma unroll
    for (int m = 0; m < 4; ++m)
#pragma unroll
        for (int n = 0; n < 4; ++n) {
            const int col = n0 + wc * 64 + n * 16 + (lane & 15);
            const int rbase = m0 + wr * 64 + m * 16 + ((lane >> 4) << 2);
#pragma unroll
            for (int j = 0; j < 4; ++j)
                C[(size_t)(rbase + j) * N + col] = s * acc[m][n][j];
        }
}

// ---------- last-resort naive path ----------
__global__ void naive_qgemm(const float* __restrict__ X, const float* __restrict__ W,
                            float* __restrict__ out, const float* __restrict__ scale_p,
                            int M) {
    const int col = blockIdx.x * 256 + threadIdx.x;
    const int row = blockIdx.y;
    const float s = *scale_p;
    const float inv = 1.0f / s;
    const float* xr = X + (size_t)row * IN_F;
    const float* wrow = W + (size_t)col * IN_F;
    float acc = 0.f;
    for (int k = 0; k < IN_F; ++k) {
        float q = fminf(fmaxf(rintf(wrow[k] * inv), -2.f), 2.f);
        acc += xr[k] * q;
    }
    out[(size_t)row * OUT_F + col] = acc * s;
}

extern "C" void kernel_launch(void* const* d_in, const int* in_sizes, int n_in,
                              void* d_out, int out_size, void* d_ws, size_t ws_size,
                              hipStream_t stream) {
    const float* x = (const float*)d_in[0];
    const float* W = (const float*)d_in[1];
    float* out = (float*)d_out;
    const int M = in_sizes[0] / IN_F;  // 8192
    const int K = IN_F, N = OUT_F;

    char* ws = (char*)d_ws;
    const size_t OFF_PART = 512;
    const size_t OFF_WQ = OFF_PART + 4096 * sizeof(float);
    const size_t WQ_BYTES = (size_t)N * K * sizeof(ushort);
    const size_t OFF_XH = OFF_WQ + WQ_BYTES;
    const size_t XH_BYTES = (size_t)M * K * sizeof(ushort);
    float* scale = (float*)(ws + 0);
    float* part = (float*)(ws + OFF_PART);
    ushort* wq = (ushort*)(ws + OFF_WQ);
    ushort* xh = (ushort*)(ws + OFF_XH);

    if (ws_size < OFF_WQ) return;

    reduce_abs1<<<4096, 256, 0, stream>>>(W, part);
    reduce_abs2<<<1, 256, 0, stream>>>(part, scale);

    if (ws_size >= OFF_XH + XH_BYTES && (M % 256) == 0 && (N % 256) == 0) {
        quantize_w<<<(N * K / 4) / 256, 256, 0, stream>>>(W, wq, scale);
        cast_x<<<(M * K / 4) / 256, 256, 0, stream>>>(x, xh);
        (void)hipFuncSetAttribute((const void*)qgemm256,
                                  hipFuncAttributeMaxDynamicSharedMemorySize,
                                  131072);
        qgemm256<<<(M / 256) * (N / 256), 512, 131072, stream>>>(
            xh, wq, out, scale, M, N, K);
    } else if (ws_size >= OFF_XH + XH_BYTES) {
        quantize_w<<<(N * K / 4) / 256, 256, 0, stream>>>(W, wq, scale);
        cast_x<<<(M * K / 4) / 256, 256, 0, stream>>>(x, xh);
        qgemm<true><<<(M / 128) * (N / 128), 256, 0, stream>>>(xh, wq, out, scale, M, N, K);
    } else if (ws_size >= OFF_WQ + WQ_BYTES) {
        quantize_w<<<(N * K / 4) / 256, 256, 0, stream>>>(W, wq, scale);
        qgemm<false><<<(M / 128) * (N / 128), 256, 0, stream>>>(x, wq, out, scale, M, N, K);
    } else {
        naive_qgemm<<<dim3(N / 256, M), 256, 0, stream>>>(x, W, out, scale, M);
    }
}